// Round 2
// baseline (5209.816 us; speedup 1.0000x reference)
//
#include <hip/hip_runtime.h>
#include <cstdint>
#include <cstddef>

// Problem constants (from reference)
#define NN   50000
#define EE   800000
#define EDIM 101
#define E2T  850000   // EE + NN (edges + self loops)

// ---------- float atomic-max encoding (monotone float->uint) ----------
__device__ __forceinline__ unsigned enc_f(float f) {
  unsigned u = __float_as_uint(f);
  return (u & 0x80000000u) ? ~u : (u | 0x80000000u);
}
__device__ __forceinline__ float dec_f(unsigned u) {
  unsigned b = (u & 0x80000000u) ? (u & 0x7fffffffu) : ~u;
  return __uint_as_float(b);
}

// ---------- preamble: per-node in-degree + segment-sum of edge_attr ----------
// 2 edges per 256-thread block; lanes 0..100 accumulate attr, lane 101 counts.
__global__ __launch_bounds__(256) void k_cnt_attr(
    const float* __restrict__ ea, const int* __restrict__ ei,
    float* __restrict__ cnt, float* __restrict__ las) {
  int e = blockIdx.x * 2 + (threadIdx.x >> 7);
  int k = threadIdx.x & 127;
  int d = ei[EE + e];
  if (k < EDIM) {
    atomicAdd(&las[(size_t)d * EDIM + k], ea[(size_t)e * EDIM + k]);
  } else if (k == EDIM) {
    atomicAdd(&cnt[d], 1.0f);
  }
}

__global__ __launch_bounds__(256) void k_rc(const float* __restrict__ cnt,
                                            float* __restrict__ rc) {
  int n = blockIdx.x * 256 + threadIdx.x;
  if (n < NN) rc[n] = 1.0f / fmaxf(cnt[n], 1.0f);
}

// ---------- generic fp32 tiled GEMM: C[M,*] = rowscale(A[M,K]) @ B[K,*] + bias ----
// 64x64 output tile per 256-thread block, full K in LDS, 4x4 register tile.
template <int K>
__global__ __launch_bounds__(256) void k_gemm(
    const float* __restrict__ A, int lda,
    const float* __restrict__ B, int ldb,
    const float* __restrict__ bias,      // may be null; indexed [col]
    const float* __restrict__ rowscale,  // may be null; indexed [row]
    float* __restrict__ C, int ldc, int M, int relu) {
  constexpr int KP = K + 1;  // LDS row pad (breaks bank aliasing)
  __shared__ float As[64 * KP];
  __shared__ float Bs[K * 64];
  int tid = threadIdx.x;
  int row0 = blockIdx.x * 64;
  int col0 = blockIdx.y * 64;

  for (int idx = tid; idx < 64 * K; idx += 256) {
    int r = idx / K, k = idx - r * K;
    int gr = row0 + r;
    As[r * KP + k] = (gr < M) ? A[(size_t)gr * lda + k] : 0.0f;
  }
  for (int idx = tid; idx < K * 64; idx += 256) {
    int k = idx >> 6, c = idx & 63;
    Bs[idx] = B[(size_t)k * ldb + col0 + c];
  }
  __syncthreads();

  int tr = tid >> 4, tc = tid & 15;
  float acc[4][4] = {};
  const float* ap = &As[tr * 4 * KP];
  const float* bp = &Bs[tc * 4];
#pragma unroll 4
  for (int k = 0; k < K; ++k) {
    float a0 = ap[k], a1 = ap[KP + k], a2 = ap[2 * KP + k], a3 = ap[3 * KP + k];
    float4 b = *(const float4*)&bp[k * 64];
    acc[0][0] += a0 * b.x; acc[0][1] += a0 * b.y; acc[0][2] += a0 * b.z; acc[0][3] += a0 * b.w;
    acc[1][0] += a1 * b.x; acc[1][1] += a1 * b.y; acc[1][2] += a1 * b.z; acc[1][3] += a1 * b.w;
    acc[2][0] += a2 * b.x; acc[2][1] += a2 * b.y; acc[2][2] += a2 * b.z; acc[2][3] += a2 * b.w;
    acc[3][0] += a3 * b.x; acc[3][1] += a3 * b.y; acc[3][2] += a3 * b.z; acc[3][3] += a3 * b.w;
  }

  float4 bv = make_float4(0.f, 0.f, 0.f, 0.f);
  if (bias) bv = *(const float4*)&bias[col0 + tc * 4];
#pragma unroll
  for (int i = 0; i < 4; ++i) {
    int r = row0 + tr * 4 + i;
    if (r >= M) break;
    float sc = rowscale ? rowscale[r] : 1.0f;
    float4 v;
    v.x = acc[i][0] * sc + bv.x;
    v.y = acc[i][1] * sc + bv.y;
    v.z = acc[i][2] * sc + bv.z;
    v.w = acc[i][3] * sc + bv.w;
    if (relu) {
      v.x = fmaxf(v.x, 0.f); v.y = fmaxf(v.y, 0.f);
      v.z = fmaxf(v.z, 0.f); v.w = fmaxf(v.w, 0.f);
    }
    *(float4*)&C[(size_t)r * ldc + col0 + tc * 4] = v;
  }
}

// ---------- edge logits (the heavy kernel) ----------
// Per block: 64 edges. Recompute ee = ea@We (K=101 GEMM, We resident in LDS),
// fuse gather of xl[src]+xr[dst], leaky-relu, att-dot, store logit, atomicMax amax.
__global__ __launch_bounds__(256) void k_edge_logit(
    const float* __restrict__ ea, const int* __restrict__ ei,
    const float* __restrict__ We, const float* __restrict__ att,
    const float* __restrict__ xl, const float* __restrict__ xr,
    float* __restrict__ logit, unsigned* __restrict__ amax) {
  constexpr int KP2 = EDIM + 1;  // 102
  __shared__ float Ws[EDIM * 128];     // 51712 B
  __shared__ float Es[64 * KP2];       // 26112 B
  int tid = threadIdx.x;
  int e0 = blockIdx.x * 64;

  for (int idx = tid; idx < (EDIM * 128) / 4; idx += 256)
    ((float4*)Ws)[idx] = ((const float4*)We)[idx];
  for (int idx = tid; idx < 64 * EDIM; idx += 256) {
    int r = idx / EDIM, k = idx - r * EDIM;
    Es[r * KP2 + k] = ea[(size_t)(e0 + r) * EDIM + k];
  }
  __syncthreads();

  int tr = tid >> 4, tc = tid & 15;
  int c0 = tc * 8;
  float acc[4][8] = {};
  const float* ep = &Es[tr * 4 * KP2];
#pragma unroll 4
  for (int k = 0; k < EDIM; ++k) {
    float a[4] = {ep[k], ep[KP2 + k], ep[2 * KP2 + k], ep[3 * KP2 + k]};
    float b[8];
    *(float4*)&b[0] = *(const float4*)&Ws[k * 128 + c0];
    *(float4*)&b[4] = *(const float4*)&Ws[k * 128 + c0 + 4];
#pragma unroll
    for (int i = 0; i < 4; ++i)
#pragma unroll
      for (int j = 0; j < 8; ++j) acc[i][j] += a[i] * b[j];
  }

  // epilogue: g = leaky(ee + xl[src] + xr[dst]); logit[e,h] = sum_c g*att
  float av[8];
  *(float4*)&av[0] = *(const float4*)&att[c0];
  *(float4*)&av[4] = *(const float4*)&att[c0 + 4];
  int h = tc >> 2;  // 8 cols per thread -> all within head tc/4
#pragma unroll
  for (int i = 0; i < 4; ++i) {
    int e = e0 + tr * 4 + i;
    int s = ei[e];
    int d = ei[EE + e];
    float xa[8], xb[8];
    *(float4*)&xa[0] = *(const float4*)&xl[(size_t)s * 128 + c0];
    *(float4*)&xa[4] = *(const float4*)&xl[(size_t)s * 128 + c0 + 4];
    *(float4*)&xb[0] = *(const float4*)&xr[(size_t)d * 128 + c0];
    *(float4*)&xb[4] = *(const float4*)&xr[(size_t)d * 128 + c0 + 4];
    float p = 0.f;
#pragma unroll
    for (int j = 0; j < 8; ++j) {
      float z = acc[i][j] + xa[j] + xb[j];
      float g = z > 0.f ? z : 0.2f * z;
      p += g * av[j];
    }
    p += __shfl_xor(p, 1);
    p += __shfl_xor(p, 2);
    if ((tc & 3) == 0) {
      logit[(size_t)e * 4 + h] = p;
      atomicMax(&amax[d * 4 + h], enc_f(p));
    }
  }
}

// ---------- self-loop logits ----------
// 2 nodes per block; 128 threads per node (one per channel).
__global__ __launch_bounds__(256) void k_loop_logit(
    const float* __restrict__ xl, const float* __restrict__ xr,
    const float* __restrict__ eel, const float* __restrict__ att,
    float* __restrict__ logit, unsigned* __restrict__ amax) {
  int n = blockIdx.x * 2 + (threadIdx.x >> 7);
  int j = threadIdx.x & 127;
  size_t o = (size_t)n * 128 + j;
  float z = xl[o] + xr[o] + eel[o];
  float g = z > 0.f ? z : 0.2f * z;
  float p = g * att[j];
  p += __shfl_xor(p, 1);  p += __shfl_xor(p, 2);  p += __shfl_xor(p, 4);
  p += __shfl_xor(p, 8);  p += __shfl_xor(p, 16);
  if ((j & 31) == 0) {
    int h = j >> 5;
    logit[(size_t)(EE + n) * 4 + h] = p;
    atomicMax(&amax[n * 4 + h], enc_f(p));
  }
}

// ---------- aggregation: out_un[d] += exp(logit-amax[d]) * xl[s]; den[d] += exp ----
// 32 lanes per edge (4 cols each), 8 edges per block. e >= EE are self loops.
__global__ __launch_bounds__(256) void k_edge_aggr(
    const int* __restrict__ ei,
    const float* __restrict__ logit, const unsigned* __restrict__ amax,
    float* __restrict__ den, const float* __restrict__ xl,
    float* __restrict__ oun) {
  int tid = threadIdx.x;
  int e = blockIdx.x * 8 + (tid >> 5);
  int sl = tid & 31;
  int c = sl * 4, h = sl >> 3;
  int s, d;
  if (e < EE) { s = ei[e]; d = ei[EE + e]; }
  else        { s = d = e - EE; }
  float lg = logit[(size_t)e * 4 + h];
  float am = dec_f(amax[d * 4 + h]);
  float ex = expf(lg - am);
  if ((sl & 7) == 0) atomicAdd(&den[d * 4 + h], ex);
  float4 v = *(const float4*)&xl[(size_t)s * 128 + c];
  atomicAdd(&oun[(size_t)d * 128 + c + 0], ex * v.x);
  atomicAdd(&oun[(size_t)d * 128 + c + 1], ex * v.y);
  atomicAdd(&oun[(size_t)d * 128 + c + 2], ex * v.z);
  atomicAdd(&oun[(size_t)d * 128 + c + 3], ex * v.w);
}

// ---------- finalize: h = relu(out_un/den + bias) ----------
__global__ __launch_bounds__(256) void k_finalize(
    const float* __restrict__ oun, const float* __restrict__ den,
    const float* __restrict__ bias, float* __restrict__ hout) {
  int idx = blockIdx.x * 256 + threadIdx.x;
  int n = idx >> 5, q = idx & 31;
  int c = q * 4, h = q >> 3;
  float dn = den[n * 4 + h] + 1e-16f;
  float rdn = 1.0f / dn;
  float4 v = *(const float4*)&oun[(size_t)n * 128 + c];
  float4 b = *(const float4*)&bias[c];
  float4 r;
  r.x = fmaxf(v.x * rdn + b.x, 0.f);
  r.y = fmaxf(v.y * rdn + b.y, 0.f);
  r.z = fmaxf(v.z * rdn + b.z, 0.f);
  r.w = fmaxf(v.w * rdn + b.w, 0.f);
  *(float4*)&hout[(size_t)n * 128 + c] = r;
}

// ---------- MLP tail: out[n] = m2[n,0:64] . W3 + b3 ----------
__global__ __launch_bounds__(256) void k_mlp3(
    const float* __restrict__ m2, const float* __restrict__ W3,
    const float* __restrict__ b3, float* __restrict__ out) {
  int n = blockIdx.x * 4 + (threadIdx.x >> 6);
  int l = threadIdx.x & 63;
  float p = m2[(size_t)n * 64 + l] * W3[l];
  p += __shfl_xor(p, 1);  p += __shfl_xor(p, 2);  p += __shfl_xor(p, 4);
  p += __shfl_xor(p, 8);  p += __shfl_xor(p, 16); p += __shfl_xor(p, 32);
  if (l == 0) out[n] = p + b3[0];
}

// =======================================================================
extern "C" void kernel_launch(void* const* d_in, const int* in_sizes, int n_in,
                              void* d_out, int out_size, void* d_ws, size_t ws_size,
                              hipStream_t stream) {
  const float* x  = (const float*)d_in[0];
  const int*   ei = (const int*)d_in[1];       // int64 in reference -> int32 from harness
  const float* ea = (const float*)d_in[2];
  const float* c1_Wl   = (const float*)d_in[3];
  const float* c1_bl   = (const float*)d_in[4];
  const float* c1_Wr   = (const float*)d_in[5];
  const float* c1_br   = (const float*)d_in[6];
  const float* c1_We   = (const float*)d_in[7];
  const float* c1_att  = (const float*)d_in[8];
  const float* c1_bias = (const float*)d_in[9];
  const float* c2_Wl   = (const float*)d_in[10];
  const float* c2_bl   = (const float*)d_in[11];
  const float* c2_Wr   = (const float*)d_in[12];
  const float* c2_br   = (const float*)d_in[13];
  const float* c2_We   = (const float*)d_in[14];
  const float* c2_att  = (const float*)d_in[15];
  const float* c2_bias = (const float*)d_in[16];
  const float* W1 = (const float*)d_in[17];
  const float* b1 = (const float*)d_in[18];
  const float* W2 = (const float*)d_in[19];
  const float* b2 = (const float*)d_in[20];
  const float* W3 = (const float*)d_in[21];
  const float* b3 = (const float*)d_in[22];
  float* out = (float*)d_out;

  // workspace layout (~164 MB total)
  char* ws = (char*)d_ws;
  size_t off = 0;
  auto alloc = [&](size_t bytes) { size_t p = off; off += (bytes + 255) & ~(size_t)255; return p; };
  size_t o_cnt   = alloc((size_t)NN * 4);
  size_t o_las   = alloc((size_t)NN * EDIM * 4);
  size_t o_rc    = alloc((size_t)NN * 4);
  size_t o_xl    = alloc((size_t)NN * 128 * 4);
  size_t o_xr    = alloc((size_t)NN * 128 * 4);
  size_t o_eel   = alloc((size_t)NN * 128 * 4);
  size_t o_logit = alloc((size_t)E2T * 4 * 4);
  size_t o_amax  = alloc((size_t)NN * 4 * 4);
  size_t o_den   = alloc((size_t)NN * 4 * 4);
  size_t o_oun   = alloc((size_t)NN * 128 * 4);
  size_t o_h     = alloc((size_t)NN * 128 * 4);
  (void)ws_size; (void)in_sizes; (void)n_in; (void)out_size;

  float*    cnt  = (float*)(ws + o_cnt);
  float*    las  = (float*)(ws + o_las);
  float*    rc   = (float*)(ws + o_rc);
  float*    xl   = (float*)(ws + o_xl);
  float*    xr   = (float*)(ws + o_xr);
  float*    eel  = (float*)(ws + o_eel);
  float*    lg   = (float*)(ws + o_logit);
  unsigned* amax = (unsigned*)(ws + o_amax);
  float*    den  = (float*)(ws + o_den);
  float*    oun  = (float*)(ws + o_oun);
  float*    hbuf = (float*)(ws + o_h);

  // ---- preamble: cnt + segment-sum(edge_attr) ----
  hipMemsetAsync(ws + o_cnt, 0, o_rc - o_cnt, stream);  // cnt + las
  k_cnt_attr<<<EE / 2, 256, 0, stream>>>(ea, ei, cnt, las);
  k_rc<<<(NN + 255) / 256, 256, 0, stream>>>(cnt, rc);

  const float* Wls[2]  = {c1_Wl, c2_Wl};
  const float* bls[2]  = {c1_bl, c2_bl};
  const float* Wrs[2]  = {c1_Wr, c2_Wr};
  const float* brs[2]  = {c1_br, c2_br};
  const float* Wes[2]  = {c1_We, c2_We};
  const float* atts[2] = {c1_att, c2_att};
  const float* bss[2]  = {c1_bias, c2_bias};

  for (int L = 0; L < 2; ++L) {
    const float* xin = (L == 0) ? x : hbuf;
    // xl = xin @ Wl + bl ; xr = xin @ Wr + br
    k_gemm<128><<<dim3(782, 2), 256, 0, stream>>>(xin, 128, Wls[L], 128, bls[L], nullptr, xl, 128, NN, 0);
    k_gemm<128><<<dim3(782, 2), 256, 0, stream>>>(xin, 128, Wrs[L], 128, brs[L], nullptr, xr, 128, NN, 0);
    // eel = (las * rc[n]) @ We   (self-loop edge transform, via linearity)
    k_gemm<EDIM><<<dim3(782, 2), 256, 0, stream>>>(las, EDIM, Wes[L], 128, nullptr, rc, eel, 128, NN, 0);
    // zero amax/den/out_un
    hipMemsetAsync(ws + o_amax, 0, o_h - o_amax, stream);
    // logits + segment max
    k_edge_logit<<<EE / 64, 256, 0, stream>>>(ea, ei, Wes[L], atts[L], xl, xr, lg, amax);
    k_loop_logit<<<NN / 2, 256, 0, stream>>>(xl, xr, eel, atts[L], lg, amax);
    // exp/den/weighted scatter
    k_edge_aggr<<<E2T / 8, 256, 0, stream>>>(ei, lg, amax, den, xl, oun);
    // h = relu(out_un/den + bias)
    k_finalize<<<(NN * 32) / 256, 256, 0, stream>>>(oun, den, bss[L], hbuf);
  }

  // ---- MLP head ----  m1 -> xl buffer, m2 -> xr buffer
  k_gemm<128><<<dim3(782, 2), 256, 0, stream>>>(hbuf, 128, W1, 128, b1, nullptr, xl, 128, NN, 1);
  k_gemm<128><<<dim3(782, 1), 256, 0, stream>>>(xl, 128, W2, 64, b2, nullptr, xr, 64, NN, 1);
  k_mlp3<<<NN / 4, 256, 0, stream>>>(xr, W3, b3, out);
}

// Round 3
// 2512.874 us; speedup vs baseline: 2.0732x; 2.0732x over previous
//
#include <hip/hip_runtime.h>
#include <cstdint>
#include <cstddef>

// Problem constants (from reference)
#define NN   50000
#define EE   800000
#define EDIM 101
#define E2T  850000   // EE + NN (edges + self loops)

// ---------- CSR build ----------
__global__ __launch_bounds__(256) void k_hist(const int* __restrict__ ei,
                                              int* __restrict__ icnt) {
  int e = blockIdx.x * 256 + threadIdx.x;
  if (e < EE) atomicAdd(&icnt[ei[EE + e]], 1);
}

// exclusive scan of icnt[NN] -> rowptr[NN]; single block of 1024 threads.
__global__ __launch_bounds__(1024) void k_scan(const int* __restrict__ icnt,
                                               int* __restrict__ rowptr) {
  __shared__ int ts[1024];
  int t = threadIdx.x;
  const int CH = (NN + 1023) / 1024;  // 49
  int base = t * CH;
  int s = 0;
  for (int i = 0; i < CH; ++i) {
    int idx = base + i;
    if (idx < NN) s += icnt[idx];
  }
  ts[t] = s;
  __syncthreads();
  for (int d = 1; d < 1024; d <<= 1) {
    int v = (t >= d) ? ts[t - d] : 0;
    __syncthreads();
    ts[t] += v;
    __syncthreads();
  }
  int run = (t == 0) ? 0 : ts[t - 1];
  for (int i = 0; i < CH; ++i) {
    int idx = base + i;
    if (idx < NN) { rowptr[idx] = run; run += icnt[idx]; }
  }
}

__global__ __launch_bounds__(256) void k_scatter(const int* __restrict__ ei,
                                                 const int* __restrict__ rowptr,
                                                 int* __restrict__ cursor,
                                                 int* __restrict__ eord) {
  int e = blockIdx.x * 256 + threadIdx.x;
  if (e >= EE) return;
  int d = ei[EE + e];
  int p = atomicAdd(&cursor[d], 1);
  eord[rowptr[d] + p] = e;
}

__global__ __launch_bounds__(256) void k_rc(const int* __restrict__ icnt,
                                            float* __restrict__ rc) {
  int n = blockIdx.x * 256 + threadIdx.x;
  if (n < NN) rc[n] = 1.0f / fmaxf((float)icnt[n], 1.0f);
}

// ---------- las[n][:] = sum over incoming edges of edge_attr (CSR gather) ----------
// 2 nodes per 256-thread block; 128 lanes per node, lanes 0..100 active.
__global__ __launch_bounds__(256) void k_las(
    const float* __restrict__ ea, const int* __restrict__ eord,
    const int* __restrict__ rowptr, const int* __restrict__ icnt,
    float* __restrict__ las) {
  int n = blockIdx.x * 2 + (threadIdx.x >> 7);
  int j = threadIdx.x & 127;
  if (j >= EDIM) return;
  int nb = rowptr[n], D = icnt[n];
  float acc = 0.f;
  for (int i = 0; i < D; ++i) {
    int e = eord[nb + i];
    acc += ea[(size_t)e * EDIM + j];
  }
  las[(size_t)n * EDIM + j] = acc;
}

// ---------- generic fp32 tiled GEMM: C[M,*] = rowscale(A[M,K]) @ B[K,*] + bias ----
template <int K>
__global__ __launch_bounds__(256) void k_gemm(
    const float* __restrict__ A, int lda,
    const float* __restrict__ B, int ldb,
    const float* __restrict__ bias,      // may be null; indexed [col]
    const float* __restrict__ rowscale,  // may be null; indexed [row]
    float* __restrict__ C, int ldc, int M, int relu) {
  constexpr int KP = K + 1;
  __shared__ float As[64 * KP];
  __shared__ float Bs[K * 64];
  int tid = threadIdx.x;
  int row0 = blockIdx.x * 64;
  int col0 = blockIdx.y * 64;

  for (int idx = tid; idx < 64 * K; idx += 256) {
    int r = idx / K, k = idx - r * K;
    int gr = row0 + r;
    As[r * KP + k] = (gr < M) ? A[(size_t)gr * lda + k] : 0.0f;
  }
  for (int idx = tid; idx < K * 64; idx += 256) {
    int k = idx >> 6, c = idx & 63;
    Bs[idx] = B[(size_t)k * ldb + col0 + c];
  }
  __syncthreads();

  int tr = tid >> 4, tc = tid & 15;
  float acc[4][4] = {};
  const float* ap = &As[tr * 4 * KP];
  const float* bp = &Bs[tc * 4];
#pragma unroll 4
  for (int k = 0; k < K; ++k) {
    float a0 = ap[k], a1 = ap[KP + k], a2 = ap[2 * KP + k], a3 = ap[3 * KP + k];
    float4 b = *(const float4*)&bp[k * 64];
    acc[0][0] += a0 * b.x; acc[0][1] += a0 * b.y; acc[0][2] += a0 * b.z; acc[0][3] += a0 * b.w;
    acc[1][0] += a1 * b.x; acc[1][1] += a1 * b.y; acc[1][2] += a1 * b.z; acc[1][3] += a1 * b.w;
    acc[2][0] += a2 * b.x; acc[2][1] += a2 * b.y; acc[2][2] += a2 * b.z; acc[2][3] += a2 * b.w;
    acc[3][0] += a3 * b.x; acc[3][1] += a3 * b.y; acc[3][2] += a3 * b.z; acc[3][3] += a3 * b.w;
  }

  float4 bv = make_float4(0.f, 0.f, 0.f, 0.f);
  if (bias) bv = *(const float4*)&bias[col0 + tc * 4];
#pragma unroll
  for (int i = 0; i < 4; ++i) {
    int r = row0 + tr * 4 + i;
    if (r >= M) break;
    float sc = rowscale ? rowscale[r] : 1.0f;
    float4 v;
    v.x = acc[i][0] * sc + bv.x;
    v.y = acc[i][1] * sc + bv.y;
    v.z = acc[i][2] * sc + bv.z;
    v.w = acc[i][3] * sc + bv.w;
    if (relu) {
      v.x = fmaxf(v.x, 0.f); v.y = fmaxf(v.y, 0.f);
      v.z = fmaxf(v.z, 0.f); v.w = fmaxf(v.w, 0.f);
    }
    *(float4*)&C[(size_t)r * ldc + col0 + tc * 4] = v;
  }
}

// ---------- edge logits ----------
// Per block: 64 edges. Recompute ee = ea@We (K=101 GEMM, We resident in LDS),
// fuse gather of xl[src]+xr[dst], leaky-relu, att-dot, store logit.
__global__ __launch_bounds__(256) void k_edge_logit(
    const float* __restrict__ ea, const int* __restrict__ ei,
    const float* __restrict__ We, const float* __restrict__ att,
    const float* __restrict__ xl, const float* __restrict__ xr,
    float* __restrict__ logit) {
  constexpr int KP2 = EDIM + 1;  // 102
  __shared__ float Ws[EDIM * 128];     // 51712 B
  __shared__ float Es[64 * KP2];       // 26112 B
  int tid = threadIdx.x;
  int e0 = blockIdx.x * 64;

  for (int idx = tid; idx < (EDIM * 128) / 4; idx += 256)
    ((float4*)Ws)[idx] = ((const float4*)We)[idx];
  for (int idx = tid; idx < 64 * EDIM; idx += 256) {
    int r = idx / EDIM, k = idx - r * EDIM;
    Es[r * KP2 + k] = ea[(size_t)(e0 + r) * EDIM + k];
  }
  __syncthreads();

  int tr = tid >> 4, tc = tid & 15;
  int c0 = tc * 8;
  float acc[4][8] = {};
  const float* ep = &Es[tr * 4 * KP2];
#pragma unroll 4
  for (int k = 0; k < EDIM; ++k) {
    float a[4] = {ep[k], ep[KP2 + k], ep[2 * KP2 + k], ep[3 * KP2 + k]};
    float b[8];
    *(float4*)&b[0] = *(const float4*)&Ws[k * 128 + c0];
    *(float4*)&b[4] = *(const float4*)&Ws[k * 128 + c0 + 4];
#pragma unroll
    for (int i = 0; i < 4; ++i)
#pragma unroll
      for (int j = 0; j < 8; ++j) acc[i][j] += a[i] * b[j];
  }

  float av[8];
  *(float4*)&av[0] = *(const float4*)&att[c0];
  *(float4*)&av[4] = *(const float4*)&att[c0 + 4];
  int h = tc >> 2;
#pragma unroll
  for (int i = 0; i < 4; ++i) {
    int e = e0 + tr * 4 + i;
    int s = ei[e];
    int d = ei[EE + e];
    float xa[8], xb[8];
    *(float4*)&xa[0] = *(const float4*)&xl[(size_t)s * 128 + c0];
    *(float4*)&xa[4] = *(const float4*)&xl[(size_t)s * 128 + c0 + 4];
    *(float4*)&xb[0] = *(const float4*)&xr[(size_t)d * 128 + c0];
    *(float4*)&xb[4] = *(const float4*)&xr[(size_t)d * 128 + c0 + 4];
    float p = 0.f;
#pragma unroll
    for (int j = 0; j < 8; ++j) {
      float z = acc[i][j] + xa[j] + xb[j];
      float g = z > 0.f ? z : 0.2f * z;
      p += g * av[j];
    }
    p += __shfl_xor(p, 1);
    p += __shfl_xor(p, 2);
    if ((tc & 3) == 0) logit[(size_t)e * 4 + h] = p;
  }
}

// ---------- self-loop logits ----------
__global__ __launch_bounds__(256) void k_loop_logit(
    const float* __restrict__ xl, const float* __restrict__ xr,
    const float* __restrict__ eel, const float* __restrict__ att,
    float* __restrict__ logit) {
  int n = blockIdx.x * 2 + (threadIdx.x >> 7);
  int j = threadIdx.x & 127;
  size_t o = (size_t)n * 128 + j;
  float z = xl[o] + xr[o] + eel[o];
  float g = z > 0.f ? z : 0.2f * z;
  float p = g * att[j];
  p += __shfl_xor(p, 1);  p += __shfl_xor(p, 2);  p += __shfl_xor(p, 4);
  p += __shfl_xor(p, 8);  p += __shfl_xor(p, 16);
  if ((j & 31) == 0) logit[(size_t)(EE + n) * 4 + (j >> 5)] = p;
}

// ---------- per-node softmax + aggregation (gather, no atomics) ----------
// One wave per node (4 nodes / 256-thread block).
// Phase A: lane-strided max over incoming logits (incl. self loop).
// Phase B: lane-strided sum of exp -> den.
// Phase C: serial edge loop; lane owns 2 channels; acc += exp * xl[src][c].
__global__ __launch_bounds__(256) void k_node_aggr(
    const int* __restrict__ ei, const int* __restrict__ eord,
    const int* __restrict__ rowptr, const int* __restrict__ icnt,
    const float* __restrict__ logit, const float* __restrict__ xl,
    const float* __restrict__ bias, float* __restrict__ hout) {
  int l = threadIdx.x & 63;
  int n = blockIdx.x * 4 + (threadIdx.x >> 6);
  int nb = rowptr[n], D = icnt[n];
  int T = D + 1;  // + self loop

  const float NEGINF = -3.0e38f;
  float m0 = NEGINF, m1 = NEGINF, m2 = NEGINF, m3 = NEGINF;
  for (int t = l; t < T; t += 64) {
    int le = (t < D) ? eord[nb + t] : (EE + n);
    float4 lv = *(const float4*)&logit[(size_t)le * 4];
    m0 = fmaxf(m0, lv.x); m1 = fmaxf(m1, lv.y);
    m2 = fmaxf(m2, lv.z); m3 = fmaxf(m3, lv.w);
  }
#pragma unroll
  for (int s = 1; s < 64; s <<= 1) {
    m0 = fmaxf(m0, __shfl_xor(m0, s));
    m1 = fmaxf(m1, __shfl_xor(m1, s));
    m2 = fmaxf(m2, __shfl_xor(m2, s));
    m3 = fmaxf(m3, __shfl_xor(m3, s));
  }

  float d0 = 0.f, d1 = 0.f, d2 = 0.f, d3 = 0.f;
  for (int t = l; t < T; t += 64) {
    int le = (t < D) ? eord[nb + t] : (EE + n);
    float4 lv = *(const float4*)&logit[(size_t)le * 4];
    d0 += __expf(lv.x - m0); d1 += __expf(lv.y - m1);
    d2 += __expf(lv.z - m2); d3 += __expf(lv.w - m3);
  }
#pragma unroll
  for (int s = 1; s < 64; s <<= 1) {
    d0 += __shfl_xor(d0, s); d1 += __shfl_xor(d1, s);
    d2 += __shfl_xor(d2, s); d3 += __shfl_xor(d3, s);
  }

  int c = l * 2;
  int h = l >> 4;  // channels 2l,2l+1 are in head (2l)/32 = l>>4
  float mh = (h == 0) ? m0 : (h == 1) ? m1 : (h == 2) ? m2 : m3;
  float acc0 = 0.f, acc1 = 0.f;
  for (int t = 0; t < T; ++t) {
    int le, s;
    if (t < D) { le = eord[nb + t]; s = ei[le]; }
    else       { le = EE + n;       s = n; }
    float ex = __expf(logit[(size_t)le * 4 + h] - mh);
    float2 v = *(const float2*)&xl[(size_t)s * 128 + c];
    acc0 += ex * v.x;
    acc1 += ex * v.y;
  }
  float dh = ((h == 0) ? d0 : (h == 1) ? d1 : (h == 2) ? d2 : d3) + 1e-16f;
  float r = 1.0f / dh;
  float2 b = *(const float2*)&bias[c];
  float2 o;
  o.x = fmaxf(acc0 * r + b.x, 0.f);
  o.y = fmaxf(acc1 * r + b.y, 0.f);
  *(float2*)&hout[(size_t)n * 128 + c] = o;
}

// ---------- MLP tail: out[n] = m2[n,0:64] . W3 + b3 ----------
__global__ __launch_bounds__(256) void k_mlp3(
    const float* __restrict__ m2, const float* __restrict__ W3,
    const float* __restrict__ b3, float* __restrict__ out) {
  int n = blockIdx.x * 4 + (threadIdx.x >> 6);
  int l = threadIdx.x & 63;
  float p = m2[(size_t)n * 64 + l] * W3[l];
  p += __shfl_xor(p, 1);  p += __shfl_xor(p, 2);  p += __shfl_xor(p, 4);
  p += __shfl_xor(p, 8);  p += __shfl_xor(p, 16); p += __shfl_xor(p, 32);
  if (l == 0) out[n] = p + b3[0];
}

// =======================================================================
extern "C" void kernel_launch(void* const* d_in, const int* in_sizes, int n_in,
                              void* d_out, int out_size, void* d_ws, size_t ws_size,
                              hipStream_t stream) {
  const float* x  = (const float*)d_in[0];
  const int*   ei = (const int*)d_in[1];       // int64 in reference -> int32 from harness
  const float* ea = (const float*)d_in[2];
  const float* c1_Wl   = (const float*)d_in[3];
  const float* c1_bl   = (const float*)d_in[4];
  const float* c1_Wr   = (const float*)d_in[5];
  const float* c1_br   = (const float*)d_in[6];
  const float* c1_We   = (const float*)d_in[7];
  const float* c1_att  = (const float*)d_in[8];
  const float* c1_bias = (const float*)d_in[9];
  const float* c2_Wl   = (const float*)d_in[10];
  const float* c2_bl   = (const float*)d_in[11];
  const float* c2_Wr   = (const float*)d_in[12];
  const float* c2_br   = (const float*)d_in[13];
  const float* c2_We   = (const float*)d_in[14];
  const float* c2_att  = (const float*)d_in[15];
  const float* c2_bias = (const float*)d_in[16];
  const float* W1 = (const float*)d_in[17];
  const float* b1 = (const float*)d_in[18];
  const float* W2 = (const float*)d_in[19];
  const float* b2 = (const float*)d_in[20];
  const float* W3 = (const float*)d_in[21];
  const float* b3 = (const float*)d_in[22];
  float* out = (float*)d_out;

  char* ws = (char*)d_ws;
  size_t off = 0;
  auto alloc = [&](size_t bytes) { size_t p = off; off += (bytes + 255) & ~(size_t)255; return p; };
  size_t o_icnt   = alloc((size_t)NN * 4);
  size_t o_cursor = alloc((size_t)NN * 4);
  size_t o_rowptr = alloc((size_t)NN * 4);
  size_t o_eord   = alloc((size_t)EE * 4);
  size_t o_rc     = alloc((size_t)NN * 4);
  size_t o_las    = alloc((size_t)NN * EDIM * 4);
  size_t o_xl     = alloc((size_t)NN * 128 * 4);
  size_t o_xr     = alloc((size_t)NN * 128 * 4);
  size_t o_eel    = alloc((size_t)NN * 128 * 4);
  size_t o_logit  = alloc((size_t)E2T * 4 * 4);
  size_t o_h      = alloc((size_t)NN * 128 * 4);
  (void)ws_size; (void)in_sizes; (void)n_in; (void)out_size;

  int*   icnt   = (int*)(ws + o_icnt);
  int*   cursor = (int*)(ws + o_cursor);
  int*   rowptr = (int*)(ws + o_rowptr);
  int*   eord   = (int*)(ws + o_eord);
  float* rc     = (float*)(ws + o_rc);
  float* las    = (float*)(ws + o_las);
  float* xl     = (float*)(ws + o_xl);
  float* xr     = (float*)(ws + o_xr);
  float* eel    = (float*)(ws + o_eel);
  float* lg     = (float*)(ws + o_logit);
  float* hbuf   = (float*)(ws + o_h);

  // ---- preamble: CSR build + per-node mean attr ----
  hipMemsetAsync(ws + o_icnt, 0, o_rowptr - o_icnt, stream);  // icnt + cursor
  k_hist<<<(EE + 255) / 256, 256, 0, stream>>>(ei, icnt);
  k_scan<<<1, 1024, 0, stream>>>(icnt, rowptr);
  k_rc<<<(NN + 255) / 256, 256, 0, stream>>>(icnt, rc);
  k_scatter<<<(EE + 255) / 256, 256, 0, stream>>>(ei, rowptr, cursor, eord);
  k_las<<<NN / 2, 256, 0, stream>>>(ea, eord, rowptr, icnt, las);

  const float* Wls[2]  = {c1_Wl, c2_Wl};
  const float* bls[2]  = {c1_bl, c2_bl};
  const float* Wrs[2]  = {c1_Wr, c2_Wr};
  const float* brs[2]  = {c1_br, c2_br};
  const float* Wes[2]  = {c1_We, c2_We};
  const float* atts[2] = {c1_att, c2_att};
  const float* bss[2]  = {c1_bias, c2_bias};

  for (int L = 0; L < 2; ++L) {
    const float* xin = (L == 0) ? x : hbuf;
    k_gemm<128><<<dim3(782, 2), 256, 0, stream>>>(xin, 128, Wls[L], 128, bls[L], nullptr, xl, 128, NN, 0);
    k_gemm<128><<<dim3(782, 2), 256, 0, stream>>>(xin, 128, Wrs[L], 128, brs[L], nullptr, xr, 128, NN, 0);
    // eel = (las * rc[n]) @ We   (self-loop edge transform, via linearity)
    k_gemm<EDIM><<<dim3(782, 2), 256, 0, stream>>>(las, EDIM, Wes[L], 128, nullptr, rc, eel, 128, NN, 0);
    k_edge_logit<<<EE / 64, 256, 0, stream>>>(ea, ei, Wes[L], atts[L], xl, xr, lg);
    k_loop_logit<<<NN / 2, 256, 0, stream>>>(xl, xr, eel, atts[L], lg);
    k_node_aggr<<<NN / 4, 256, 0, stream>>>(ei, eord, rowptr, icnt, lg, xl, bss[L], hbuf);
  }

  // ---- MLP head ----
  k_gemm<128><<<dim3(782, 2), 256, 0, stream>>>(hbuf, 128, W1, 128, b1, nullptr, xl, 128, NN, 1);
  k_gemm<128><<<dim3(782, 1), 256, 0, stream>>>(xl, 128, W2, 64, b2, nullptr, xr, 64, NN, 1);
  k_mlp3<<<NN / 4, 256, 0, stream>>>(xr, W3, b3, out);
}

// Round 4
// 2303.290 us; speedup vs baseline: 2.2619x; 1.0910x over previous
//
#include <hip/hip_runtime.h>
#include <cstdint>
#include <cstddef>

// Problem constants (from reference)
#define NN   50000
#define EE   800000
#define EDIM 101
#define E2T  850000   // EE + NN (edges + self loops)
#define KPB  128      // padded K for bf16 edge-attr buffers

typedef __attribute__((ext_vector_type(8))) short s8v;
typedef __attribute__((ext_vector_type(4))) float f4v;

// ---------- fp32 <-> bf16 helpers (RNE) ----------
__device__ __forceinline__ unsigned short f2bf(float x) {
  unsigned u = __float_as_uint(x);
  unsigned r = (u + 0x7fffu + ((u >> 16) & 1u)) >> 16;
  return (unsigned short)r;
}
__device__ __forceinline__ float bf2f(unsigned short b) {
  return __uint_as_float(((unsigned)b) << 16);
}

// ---------- CSR build ----------
__global__ __launch_bounds__(256) void k_hist(const int* __restrict__ ei,
                                              int* __restrict__ icnt) {
  int e = blockIdx.x * 256 + threadIdx.x;
  if (e < EE) atomicAdd(&icnt[ei[EE + e]], 1);
}

__global__ __launch_bounds__(1024) void k_scan(const int* __restrict__ icnt,
                                               int* __restrict__ rowptr) {
  __shared__ int ts[1024];
  int t = threadIdx.x;
  const int CH = (NN + 1023) / 1024;  // 49
  int base = t * CH;
  int s = 0;
  for (int i = 0; i < CH; ++i) {
    int idx = base + i;
    if (idx < NN) s += icnt[idx];
  }
  ts[t] = s;
  __syncthreads();
  for (int d = 1; d < 1024; d <<= 1) {
    int v = (t >= d) ? ts[t - d] : 0;
    __syncthreads();
    ts[t] += v;
    __syncthreads();
  }
  int run = (t == 0) ? 0 : ts[t - 1];
  for (int i = 0; i < CH; ++i) {
    int idx = base + i;
    if (idx < NN) { rowptr[idx] = run; run += icnt[idx]; }
  }
}

__global__ __launch_bounds__(256) void k_scatter(const int* __restrict__ ei,
                                                 const int* __restrict__ rowptr,
                                                 int* __restrict__ cursor,
                                                 int* __restrict__ eord) {
  int e = blockIdx.x * 256 + threadIdx.x;
  if (e >= EE) return;
  int d = ei[EE + e];
  int p = atomicAdd(&cursor[d], 1);
  eord[rowptr[d] + p] = e;
}

__global__ __launch_bounds__(256) void k_rc(const int* __restrict__ icnt,
                                            float* __restrict__ rc) {
  int n = blockIdx.x * 256 + threadIdx.x;
  if (n < NN) rc[n] = 1.0f / fmaxf((float)icnt[n], 1.0f);
}

// ---------- las[n][:] = sum over incoming edges of edge_attr (CSR gather) ----------
__global__ __launch_bounds__(256) void k_las(
    const float* __restrict__ ea, const int* __restrict__ eord,
    const int* __restrict__ rowptr, const int* __restrict__ icnt,
    float* __restrict__ las) {
  int n = blockIdx.x * 2 + (threadIdx.x >> 7);
  int j = threadIdx.x & 127;
  if (j >= EDIM) return;
  int nb = rowptr[n], D = icnt[n];
  float acc = 0.f;
  for (int i = 0; i < D; ++i) {
    int e = eord[nb + i];
    acc += ea[(size_t)e * EDIM + j];
  }
  las[(size_t)n * EDIM + j] = acc;
}

// ---------- prepass: ea fp32 -> (hi,lo) bf16, K padded 101->128, zeros in tail ----
__global__ __launch_bounds__(256) void k_cvt(
    const float* __restrict__ ea,
    unsigned short* __restrict__ eaH, unsigned short* __restrict__ eaL) {
  int idx = blockIdx.x * 256 + threadIdx.x;   // EE*32 total
  int e = idx >> 5, kq = idx & 31;
  int k = kq * 4;
  unsigned short h[4], l[4];
#pragma unroll
  for (int j = 0; j < 4; ++j) {
    float v = (k + j < EDIM) ? ea[(size_t)e * EDIM + k + j] : 0.0f;
    unsigned short hb = f2bf(v);
    h[j] = hb;
    l[j] = f2bf(v - bf2f(hb));
  }
  uint2 hp, lp;
  hp.x = (unsigned)h[0] | ((unsigned)h[1] << 16);
  hp.y = (unsigned)h[2] | ((unsigned)h[3] << 16);
  lp.x = (unsigned)l[0] | ((unsigned)l[1] << 16);
  lp.y = (unsigned)l[2] | ((unsigned)l[3] << 16);
  *(uint2*)&eaH[(size_t)e * KPB + k] = hp;
  *(uint2*)&eaL[(size_t)e * KPB + k] = lp;
}

// ---------- generic fp32 tiled GEMM (unchanged) ----------
template <int K>
__global__ __launch_bounds__(256) void k_gemm(
    const float* __restrict__ A, int lda,
    const float* __restrict__ B, int ldb,
    const float* __restrict__ bias,
    const float* __restrict__ rowscale,
    float* __restrict__ C, int ldc, int M, int relu) {
  constexpr int KP = K + 1;
  __shared__ float As[64 * KP];
  __shared__ float Bs[K * 64];
  int tid = threadIdx.x;
  int row0 = blockIdx.x * 64;
  int col0 = blockIdx.y * 64;

  for (int idx = tid; idx < 64 * K; idx += 256) {
    int r = idx / K, k = idx - r * K;
    int gr = row0 + r;
    As[r * KP + k] = (gr < M) ? A[(size_t)gr * lda + k] : 0.0f;
  }
  for (int idx = tid; idx < K * 64; idx += 256) {
    int k = idx >> 6, c = idx & 63;
    Bs[idx] = B[(size_t)k * ldb + col0 + c];
  }
  __syncthreads();

  int tr = tid >> 4, tc = tid & 15;
  float acc[4][4] = {};
  const float* ap = &As[tr * 4 * KP];
  const float* bp = &Bs[tc * 4];
#pragma unroll 4
  for (int k = 0; k < K; ++k) {
    float a0 = ap[k], a1 = ap[KP + k], a2 = ap[2 * KP + k], a3 = ap[3 * KP + k];
    float4 b = *(const float4*)&bp[k * 64];
    acc[0][0] += a0 * b.x; acc[0][1] += a0 * b.y; acc[0][2] += a0 * b.z; acc[0][3] += a0 * b.w;
    acc[1][0] += a1 * b.x; acc[1][1] += a1 * b.y; acc[1][2] += a1 * b.z; acc[1][3] += a1 * b.w;
    acc[2][0] += a2 * b.x; acc[2][1] += a2 * b.y; acc[2][2] += a2 * b.z; acc[2][3] += a2 * b.w;
    acc[3][0] += a3 * b.x; acc[3][1] += a3 * b.y; acc[3][2] += a3 * b.z; acc[3][3] += a3 * b.w;
  }

  float4 bv = make_float4(0.f, 0.f, 0.f, 0.f);
  if (bias) bv = *(const float4*)&bias[col0 + tc * 4];
#pragma unroll
  for (int i = 0; i < 4; ++i) {
    int r = row0 + tr * 4 + i;
    if (r >= M) break;
    float sc = rowscale ? rowscale[r] : 1.0f;
    float4 v;
    v.x = acc[i][0] * sc + bv.x;
    v.y = acc[i][1] * sc + bv.y;
    v.z = acc[i][2] * sc + bv.z;
    v.w = acc[i][3] * sc + bv.w;
    if (relu) {
      v.x = fmaxf(v.x, 0.f); v.y = fmaxf(v.y, 0.f);
      v.z = fmaxf(v.z, 0.f); v.w = fmaxf(v.w, 0.f);
    }
    *(float4*)&C[(size_t)r * ldc + col0 + tc * 4] = v;
  }
}

// ---------- edge logits via 3xBF16 MFMA (emulated fp32) ----------
// Block: 128 edges x 128 cols. Wave w owns m-tiles {2w,2w+1}, all 8 n-tiles.
// A-frags (eaH/eaL) direct from global; We hi/lo staged in LDS in
// fragment-contiguous tiled layout (conflict-free ds_read_b128).
// Epilogue: g=leaky(ee+xl[src]+xr[dst]); logit[e][h]=sum_c g*att; float4 write.
__global__ __launch_bounds__(256) void k_edge_logit_mfma(
    const unsigned short* __restrict__ eaH, const unsigned short* __restrict__ eaL,
    const int* __restrict__ ei, const float* __restrict__ We,
    const float* __restrict__ att,
    const float* __restrict__ xl, const float* __restrict__ xr,
    float* __restrict__ logit) {
  __shared__ __align__(16) unsigned short BH[16384];  // 32 KB (8nt x 4ks x 64 lane x 8)
  __shared__ __align__(16) unsigned short BL[16384];  // 32 KB
  __shared__ int sdl[128], sdr[128];

  int tid = threadIdx.x;
  int e0 = blockIdx.x * 128;

  if (tid < 128) {
    sdl[tid] = ei[e0 + tid];
    sdr[tid] = ei[EE + e0 + tid];
  }
  // stage We -> BH/BL in tiled fragment order
  for (int idx = tid; idx < 2048; idx += 256) {
    int n = idx & 127, kg = idx >> 7;          // kg in [0,16)
    int nt = n >> 4, ln0 = n & 15, ks = kg >> 2, q0 = kg & 3;
    s8v h8, l8;
#pragma unroll
    for (int j = 0; j < 8; ++j) {
      int k = kg * 8 + j;
      float v = (k < EDIM) ? We[(size_t)k * 128 + n] : 0.0f;
      unsigned short hb = f2bf(v);
      h8[j] = (short)hb;
      l8[j] = (short)f2bf(v - bf2f(hb));
    }
    int off = ((nt * 4 + ks) * 64 + q0 * 16 + ln0) * 8;
    *(s8v*)&BH[off] = h8;
    *(s8v*)&BL[off] = l8;
  }
  __syncthreads();

  int w = tid >> 6, lane = tid & 63;
  int ln = lane & 15, q = lane >> 4;

  f4v acc[2][8];
#pragma unroll
  for (int m = 0; m < 2; ++m)
#pragma unroll
    for (int nt = 0; nt < 8; ++nt) acc[m][nt] = (f4v){0.f, 0.f, 0.f, 0.f};

#pragma unroll
  for (int ks = 0; ks < 4; ++ks) {
    s8v ah[2], al[2];
#pragma unroll
    for (int m = 0; m < 2; ++m) {
      size_t ao = (size_t)(e0 + (w * 2 + m) * 16 + ln) * KPB + ks * 32 + q * 8;
      ah[m] = *(const s8v*)&eaH[ao];
      al[m] = *(const s8v*)&eaL[ao];
    }
#pragma unroll
    for (int nt = 0; nt < 8; ++nt) {
      int off = ((nt * 4 + ks) * 64 + lane) * 8;
      s8v bh = *(const s8v*)&BH[off];
      s8v bl = *(const s8v*)&BL[off];
#pragma unroll
      for (int m = 0; m < 2; ++m) {
        acc[m][nt] = __builtin_amdgcn_mfma_f32_16x16x32_bf16(ah[m], bh, acc[m][nt], 0, 0, 0);
        acc[m][nt] = __builtin_amdgcn_mfma_f32_16x16x32_bf16(ah[m], bl, acc[m][nt], 0, 0, 0);
        acc[m][nt] = __builtin_amdgcn_mfma_f32_16x16x32_bf16(al[m], bh, acc[m][nt], 0, 0, 0);
      }
    }
  }

  // epilogue
  float attv[8];
#pragma unroll
  for (int nt = 0; nt < 8; ++nt) attv[nt] = att[nt * 16 + ln];

#pragma unroll
  for (int m = 0; m < 2; ++m) {
    int mt = w * 2 + m;
#pragma unroll
    for (int i = 0; i < 4; ++i) {
      int er = mt * 16 + q * 4 + i;  // C layout: row = quad*4 + reg
      int e = e0 + er;
      int s = sdl[er], d = sdr[er];
      float ph0 = 0.f, ph1 = 0.f, ph2 = 0.f, ph3 = 0.f;
#pragma unroll
      for (int nt = 0; nt < 8; ++nt) {
        int col = nt * 16 + ln;
        float z = acc[m][nt][i] + xl[(size_t)s * 128 + col] + xr[(size_t)d * 128 + col];
        float g = z > 0.f ? z : 0.2f * z;
        float t = g * attv[nt];
        if (nt < 2) ph0 += t; else if (nt < 4) ph1 += t;
        else if (nt < 6) ph2 += t; else ph3 += t;
      }
      ph0 += __shfl_xor(ph0, 1); ph0 += __shfl_xor(ph0, 2);
      ph0 += __shfl_xor(ph0, 4); ph0 += __shfl_xor(ph0, 8);
      ph1 += __shfl_xor(ph1, 1); ph1 += __shfl_xor(ph1, 2);
      ph1 += __shfl_xor(ph1, 4); ph1 += __shfl_xor(ph1, 8);
      ph2 += __shfl_xor(ph2, 1); ph2 += __shfl_xor(ph2, 2);
      ph2 += __shfl_xor(ph2, 4); ph2 += __shfl_xor(ph2, 8);
      ph3 += __shfl_xor(ph3, 1); ph3 += __shfl_xor(ph3, 2);
      ph3 += __shfl_xor(ph3, 4); ph3 += __shfl_xor(ph3, 8);
      if (ln == 0)
        *(float4*)&logit[(size_t)e * 4] = make_float4(ph0, ph1, ph2, ph3);
    }
  }
}

// ---------- self-loop logits ----------
__global__ __launch_bounds__(256) void k_loop_logit(
    const float* __restrict__ xl, const float* __restrict__ xr,
    const float* __restrict__ eel, const float* __restrict__ att,
    float* __restrict__ logit) {
  int n = blockIdx.x * 2 + (threadIdx.x >> 7);
  int j = threadIdx.x & 127;
  size_t o = (size_t)n * 128 + j;
  float z = xl[o] + xr[o] + eel[o];
  float g = z > 0.f ? z : 0.2f * z;
  float p = g * att[j];
  p += __shfl_xor(p, 1);  p += __shfl_xor(p, 2);  p += __shfl_xor(p, 4);
  p += __shfl_xor(p, 8);  p += __shfl_xor(p, 16);
  if ((j & 31) == 0) logit[(size_t)(EE + n) * 4 + (j >> 5)] = p;
}

// ---------- per-node softmax + aggregation (gather, no atomics) ----------
__global__ __launch_bounds__(256) void k_node_aggr(
    const int* __restrict__ ei, const int* __restrict__ eord,
    const int* __restrict__ rowptr, const int* __restrict__ icnt,
    const float* __restrict__ logit, const float* __restrict__ xl,
    const float* __restrict__ bias, float* __restrict__ hout) {
  int l = threadIdx.x & 63;
  int n = blockIdx.x * 4 + (threadIdx.x >> 6);
  int nb = rowptr[n], D = icnt[n];
  int T = D + 1;  // + self loop

  const float NEGINF = -3.0e38f;
  float m0 = NEGINF, m1 = NEGINF, m2 = NEGINF, m3 = NEGINF;
  for (int t = l; t < T; t += 64) {
    int le = (t < D) ? eord[nb + t] : (EE + n);
    float4 lv = *(const float4*)&logit[(size_t)le * 4];
    m0 = fmaxf(m0, lv.x); m1 = fmaxf(m1, lv.y);
    m2 = fmaxf(m2, lv.z); m3 = fmaxf(m3, lv.w);
  }
#pragma unroll
  for (int s = 1; s < 64; s <<= 1) {
    m0 = fmaxf(m0, __shfl_xor(m0, s));
    m1 = fmaxf(m1, __shfl_xor(m1, s));
    m2 = fmaxf(m2, __shfl_xor(m2, s));
    m3 = fmaxf(m3, __shfl_xor(m3, s));
  }

  float d0 = 0.f, d1 = 0.f, d2 = 0.f, d3 = 0.f;
  for (int t = l; t < T; t += 64) {
    int le = (t < D) ? eord[nb + t] : (EE + n);
    float4 lv = *(const float4*)&logit[(size_t)le * 4];
    d0 += __expf(lv.x - m0); d1 += __expf(lv.y - m1);
    d2 += __expf(lv.z - m2); d3 += __expf(lv.w - m3);
  }
#pragma unroll
  for (int s = 1; s < 64; s <<= 1) {
    d0 += __shfl_xor(d0, s); d1 += __shfl_xor(d1, s);
    d2 += __shfl_xor(d2, s); d3 += __shfl_xor(d3, s);
  }

  int c = l * 2;
  int h = l >> 4;
  float mh = (h == 0) ? m0 : (h == 1) ? m1 : (h == 2) ? m2 : m3;
  float acc0 = 0.f, acc1 = 0.f;
  for (int t = 0; t < T; ++t) {
    int le, s;
    if (t < D) { le = eord[nb + t]; s = ei[le]; }
    else       { le = EE + n;       s = n; }
    float ex = __expf(logit[(size_t)le * 4 + h] - mh);
    float2 v = *(const float2*)&xl[(size_t)s * 128 + c];
    acc0 += ex * v.x;
    acc1 += ex * v.y;
  }
  float dh = ((h == 0) ? d0 : (h == 1) ? d1 : (h == 2) ? d2 : d3) + 1e-16f;
  float r = 1.0f / dh;
  float2 b = *(const float2*)&bias[c];
  float2 o;
  o.x = fmaxf(acc0 * r + b.x, 0.f);
  o.y = fmaxf(acc1 * r + b.y, 0.f);
  *(float2*)&hout[(size_t)n * 128 + c] = o;
}

// ---------- MLP tail ----------
__global__ __launch_bounds__(256) void k_mlp3(
    const float* __restrict__ m2, const float* __restrict__ W3,
    const float* __restrict__ b3, float* __restrict__ out) {
  int n = blockIdx.x * 4 + (threadIdx.x >> 6);
  int l = threadIdx.x & 63;
  float p = m2[(size_t)n * 64 + l] * W3[l];
  p += __shfl_xor(p, 1);  p += __shfl_xor(p, 2);  p += __shfl_xor(p, 4);
  p += __shfl_xor(p, 8);  p += __shfl_xor(p, 16); p += __shfl_xor(p, 32);
  if (l == 0) out[n] = p + b3[0];
}

// =======================================================================
extern "C" void kernel_launch(void* const* d_in, const int* in_sizes, int n_in,
                              void* d_out, int out_size, void* d_ws, size_t ws_size,
                              hipStream_t stream) {
  const float* x  = (const float*)d_in[0];
  const int*   ei = (const int*)d_in[1];       // int64 in reference -> int32 from harness
  const float* ea = (const float*)d_in[2];
  const float* c1_Wl   = (const float*)d_in[3];
  const float* c1_bl   = (const float*)d_in[4];
  const float* c1_Wr   = (const float*)d_in[5];
  const float* c1_br   = (const float*)d_in[6];
  const float* c1_We   = (const float*)d_in[7];
  const float* c1_att  = (const float*)d_in[8];
  const float* c1_bias = (const float*)d_in[9];
  const float* c2_Wl   = (const float*)d_in[10];
  const float* c2_bl   = (const float*)d_in[11];
  const float* c2_Wr   = (const float*)d_in[12];
  const float* c2_br   = (const float*)d_in[13];
  const float* c2_We   = (const float*)d_in[14];
  const float* c2_att  = (const float*)d_in[15];
  const float* c2_bias = (const float*)d_in[16];
  const float* W1 = (const float*)d_in[17];
  const float* b1 = (const float*)d_in[18];
  const float* W2 = (const float*)d_in[19];
  const float* b2 = (const float*)d_in[20];
  const float* W3 = (const float*)d_in[21];
  const float* b3 = (const float*)d_in[22];
  float* out = (float*)d_out;

  char* ws = (char*)d_ws;
  size_t off = 0;
  auto alloc = [&](size_t bytes) { size_t p = off; off += (bytes + 255) & ~(size_t)255; return p; };
  size_t o_icnt   = alloc((size_t)NN * 4);
  size_t o_cursor = alloc((size_t)NN * 4);
  size_t o_rowptr = alloc((size_t)NN * 4);
  size_t o_eord   = alloc((size_t)EE * 4);
  size_t o_rc     = alloc((size_t)NN * 4);
  size_t o_las    = alloc((size_t)NN * EDIM * 4);
  size_t o_xl     = alloc((size_t)NN * 128 * 4);
  size_t o_xr     = alloc((size_t)NN * 128 * 4);
  size_t o_eel    = alloc((size_t)NN * 128 * 4);
  size_t o_logit  = alloc((size_t)E2T * 4 * 4);
  size_t o_h      = alloc((size_t)NN * 128 * 4);
  size_t o_eaH    = alloc((size_t)EE * KPB * 2);
  size_t o_eaL    = alloc((size_t)EE * KPB * 2);
  (void)ws_size; (void)in_sizes; (void)n_in; (void)out_size;

  int*   icnt   = (int*)(ws + o_icnt);
  int*   cursor = (int*)(ws + o_cursor);
  int*   rowptr = (int*)(ws + o_rowptr);
  int*   eord   = (int*)(ws + o_eord);
  float* rc     = (float*)(ws + o_rc);
  float* las    = (float*)(ws + o_las);
  float* xl     = (float*)(ws + o_xl);
  float* xr     = (float*)(ws + o_xr);
  float* eel    = (float*)(ws + o_eel);
  float* lg     = (float*)(ws + o_logit);
  float* hbuf   = (float*)(ws + o_h);
  unsigned short* eaH = (unsigned short*)(ws + o_eaH);
  unsigned short* eaL = (unsigned short*)(ws + o_eaL);

  // ---- preamble: CSR build + per-node mean attr + bf16 split of ea ----
  hipMemsetAsync(ws + o_icnt, 0, o_rowptr - o_icnt, stream);  // icnt + cursor
  k_hist<<<(EE + 255) / 256, 256, 0, stream>>>(ei, icnt);
  k_scan<<<1, 1024, 0, stream>>>(icnt, rowptr);
  k_rc<<<(NN + 255) / 256, 256, 0, stream>>>(icnt, rc);
  k_scatter<<<(EE + 255) / 256, 256, 0, stream>>>(ei, rowptr, cursor, eord);
  k_las<<<NN / 2, 256, 0, stream>>>(ea, eord, rowptr, icnt, las);
  k_cvt<<<(EE * 32) / 256, 256, 0, stream>>>(ea, eaH, eaL);

  const float* Wls[2]  = {c1_Wl, c2_Wl};
  const float* bls[2]  = {c1_bl, c2_bl};
  const float* Wrs[2]  = {c1_Wr, c2_Wr};
  const float* brs[2]  = {c1_br, c2_br};
  const float* Wes[2]  = {c1_We, c2_We};
  const float* atts[2] = {c1_att, c2_att};
  const float* bss[2]  = {c1_bias, c2_bias};

  for (int L = 0; L < 2; ++L) {
    const float* xin = (L == 0) ? x : hbuf;
    k_gemm<128><<<dim3(782, 2), 256, 0, stream>>>(xin, 128, Wls[L], 128, bls[L], nullptr, xl, 128, NN, 0);
    k_gemm<128><<<dim3(782, 2), 256, 0, stream>>>(xin, 128, Wrs[L], 128, brs[L], nullptr, xr, 128, NN, 0);
    // eel = (las * rc[n]) @ We   (self-loop edge transform, via linearity)
    k_gemm<EDIM><<<dim3(782, 2), 256, 0, stream>>>(las, EDIM, Wes[L], 128, nullptr, rc, eel, 128, NN, 0);
    k_edge_logit_mfma<<<EE / 128, 256, 0, stream>>>(eaH, eaL, ei, Wes[L], atts[L], xl, xr, lg);
    k_loop_logit<<<NN / 2, 256, 0, stream>>>(xl, xr, eel, atts[L], lg);
    k_node_aggr<<<NN / 4, 256, 0, stream>>>(ei, eord, rowptr, icnt, lg, xl, bss[L], hbuf);
  }

  // ---- MLP head ----
  k_gemm<128><<<dim3(782, 2), 256, 0, stream>>>(hbuf, 128, W1, 128, b1, nullptr, xl, 128, NN, 1);
  k_gemm<128><<<dim3(782, 1), 256, 0, stream>>>(xl, 128, W2, 64, b2, nullptr, xr, 64, NN, 1);
  k_mlp3<<<NN / 4, 256, 0, stream>>>(xr, W3, b3, out);
}